// Round 16
// baseline (165.157 us; speedup 1.0000x reference)
//
#include <hip/hip_runtime.h>
#include <cstdint>
#include <cstddef>

// Problem constants (fixed by the reference setup)
#define NNODES 2000
#define TSTEPS 8
#define NHEADS 4
#define CAP    96      // max neighbors; degree ~ Binom(2000,0.01)+self ≈ 21±4.5, 96 is >16σ
#define NROWS  (TSTEPS * NNODES)   // 16000

// ---------------------------------------------------------------------------
// K1: blocks [0,NROWS) build CSR rows (float4 scan + 4 ordered ballots);
//     blocks [NROWS,2*NROWS) compute layer-1 GAT projection h1/es1/ed1.
__global__ void k1_csr_gath1(const float* __restrict__ A,
                             int* __restrict__ nbr, int* __restrict__ cnt,
                             const float* __restrict__ feats,
                             const float* __restrict__ W, const float* __restrict__ a,
                             float* __restrict__ hbuf, float* __restrict__ es,
                             float* __restrict__ ed) {
    const int lane = threadIdx.x;            // 64
    if (blockIdx.x < NROWS) {
        const int row = blockIdx.x;          // t*N + n
        const float4* Ar4 = reinterpret_cast<const float4*>(A + (size_t)row * NNODES);
        int* outp = nbr + (size_t)row * CAP;
        const unsigned long long lmask = (1ull << lane) - 1ull;
        int c = 0;
        for (int j4 = lane; j4 < NNODES / 4; j4 += 64) {   // 500 float4 per row
            float4 v = Ar4[j4];
            #pragma unroll
            for (int cc = 0; cc < 4; ++cc) {
                float x = (cc == 0) ? v.x : (cc == 1) ? v.y : (cc == 2) ? v.z : v.w;
                bool p = x > 0.0f;
                unsigned long long m = __ballot(p);
                int off = __popcll(m & lmask);
                if (p && c + off < CAP) outp[c + off] = j4 * 4 + cc;
                c += (int)__popcll(m);
            }
        }
        if (lane == 0) cnt[row] = (c > CAP ? CAP : c);
    } else {
        const int b = blockIdx.x - NROWS;    // t*N + n
        const int t = b / NNODES, n = b % NNODES;
        constexpr int F = 32, D = 16;
        const int h = lane / D, d = lane % D;
        const float* xr = feats + (size_t)b * F;
        const float* Wp = W + (size_t)h * F * D + d;
        float acc = 0.f;
        #pragma unroll
        for (int f = 0; f < F; ++f) acc += xr[f] * Wp[f * D];
        hbuf[(((size_t)t * NHEADS + h) * NNODES + n) * D + d] = acc;
        float s0 = acc * a[(h * 2 + 0) * D + d];
        float s1 = acc * a[(h * 2 + 1) * D + d];
        #pragma unroll
        for (int s = D / 2; s > 0; s >>= 1) {
            s0 += __shfl_down(s0, s, D);
            s1 += __shfl_down(s1, s, D);
        }
        if (d == 0) {
            es[((size_t)t * NHEADS + h) * NNODES + n] = s0;
            ed[((size_t)t * NHEADS + h) * NNODES + n] = s1;
        }
    }
}

// ---------------------------------------------------------------------------
// K2/K4: sparse softmax + aggregate, all t, no-max (R15) + exp folded into
// the PARALLEL staging loop: eds now stores exp(leaky(esv+ed)) so the serial
// loop is pure {wsum += w; acc += w*gather}. Same per-element formula and
// same k-ascending sum order -> bit-identical output.
template<int D, bool CONCAT>
__global__ void gat_attn_all_kernel(const int* __restrict__ nbr, const int* __restrict__ cnt_arr,
                                    const float* __restrict__ hbuf, const float* __restrict__ es,
                                    const float* __restrict__ ed, float* __restrict__ Z) {
    const int b = blockIdx.x;
    const int t = b / NNODES, n = b % NNODES;
    const int tid = threadIdx.x;
    const int h = tid / D, d = tid % D;
    const int cnt = cnt_arr[b];
    const int* idx = nbr + (size_t)b * CAP;
    const float* esb = es + (size_t)t * NHEADS * NNODES;
    const float* edb = ed + (size_t)t * NHEADS * NNODES;
    const float* hb  = hbuf + (size_t)t * NHEADS * NNODES * D;
    __shared__ int mlist[CAP];
    __shared__ float eds[NHEADS][CAP];
    for (int k = tid; k < cnt; k += NHEADS * D) mlist[k] = idx[k];
    __syncthreads();
    const float esv = esb[(size_t)h * NNODES + n];
    for (int k = d; k < cnt; k += D) {
        float v = esv + edb[(size_t)h * NNODES + mlist[k]];
        v = v > 0.f ? v : 0.2f * v;          // leaky_relu(0.2)
        eds[h][k] = __expf(v);               // shift-invariant softmax: no max
    }
    __syncthreads();
    float wsum = 0.f, acc = 0.f;
    for (int k = 0; k < cnt; ++k) {
        float w = eds[h][k];
        wsum += w;
        acc += w * hb[((size_t)h * NNODES + mlist[k]) * D + d];
    }
    float o = acc / wsum;
    if constexpr (CONCAT) {
        float e = o > 0.f ? o : (__expf(o) - 1.0f);       // elu
        Z[(size_t)b * (NHEADS * D) + h * D + d] = e;      // [T][N][H*D]
    } else {
        __shared__ float red[NHEADS][D];
        red[h][d] = o;
        __syncthreads();
        if (h == 0) Z[(size_t)b * D + d] =
            (red[0][d] + red[1][d] + red[2][d] + red[3][d]) * 0.25f;  // mean heads, no elu
    }
}

// ---------------------------------------------------------------------------
// K3: layer-1 fused wz+GRU (D=64) + layer-2 GAT projection epilogue.
// NEW: U lives in LDS (one bulk coalesced stage at entry, conflict-free
// per-thread-slot layout u4[g][c][tid]) so the serial GRU phase touches ZERO
// global memory. W streams per-gate through 16 transient registers (dead
// after its 8 dots). W2 reuses the U buffer after the GRU. Thread mapping
// and phase structure are R7/R15's proven best; only the weight data path
// changes. Per-block global-dependency waits drop from ~tens to ~5 bulk.
__global__ __launch_bounds__(256, 1)
void wzgru1_gath2_kernel(const float* __restrict__ Wg, const float* __restrict__ Ug,
                         const float* __restrict__ bg, const float* __restrict__ Z,
                         const float* __restrict__ q0,
                         const float* __restrict__ W2, const float* __restrict__ a2,
                         float* __restrict__ h2, float* __restrict__ es2,
                         float* __restrict__ ed2) {
    constexpr int D = 64;
    constexpr int TPB = 256;
    constexpr int F4R = D / 4;               // float4 per matrix row
    const int n = blockIdx.x, tid = threadIdx.x;
    const int quad = tid & 3;
    const int row  = tid >> 2;
    const int cbase = quad * 16;
    __shared__ float Zs[TSTEPS][D];          // 2 KB
    __shared__ float Qh[TSTEPS][D];          // 2 KB
    __shared__ float Qs[D], rq[D];           // 0.5 KB
    __shared__ float4 u4[3][4][TPB];         // 48 KB: U resident; reused for W2

    // ---- entry: bulk-stage U -> LDS (conflict-free slots), Z, Q0, bias ----
    float4 ureg[3][4];
    #pragma unroll
    for (int g = 0; g < 3; ++g) {
        const float4* U4 = reinterpret_cast<const float4*>(
            Ug + ((size_t)g * NNODES + n) * D * D + (size_t)row * D + cbase);
        #pragma unroll
        for (int c = 0; c < 4; ++c) ureg[g][c] = U4[c];
    }
    for (int idx = tid; idx < TSTEPS * F4R; idx += TPB) {
        int t = idx / F4R, i4 = idx % F4R;
        reinterpret_cast<float4*>(&Zs[t][0])[i4] =
            reinterpret_cast<const float4*>(Z + ((size_t)t * NNODES + n) * D)[i4];
    }
    if (tid < D) Qs[tid] = q0[(size_t)n * D + tid];
    float bgv[3];
    #pragma unroll
    for (int g = 0; g < 3; ++g) bgv[g] = bg[((size_t)g * NNODES + n) * D + row];
    #pragma unroll
    for (int g = 0; g < 3; ++g)
        #pragma unroll
        for (int c = 0; c < 4; ++c) u4[g][c][tid] = ureg[g][c];
    __syncthreads();   // Zs, Qs, u4 ready

    // ---- Phase B: wz[g][t] -> registers; W streamed per gate (16 transient
    //      regs); dot order per (g,t) identical to R15 -> bit-identical ----
    float wzr[3][TSTEPS];
    #pragma unroll
    for (int g = 0; g < 3; ++g) {
        float wseg[16];
        const float4* W4 = reinterpret_cast<const float4*>(
            Wg + ((size_t)g * NNODES + n) * D * D + (size_t)row * D + cbase);
        #pragma unroll
        for (int c = 0; c < 4; ++c) {
            float4 v = W4[c];
            wseg[c * 4 + 0] = v.x; wseg[c * 4 + 1] = v.y;
            wseg[c * 4 + 2] = v.z; wseg[c * 4 + 3] = v.w;
        }
        #pragma unroll
        for (int t = 0; t < TSTEPS; ++t) {
            float z16[16];
            #pragma unroll
            for (int c = 0; c < 4; ++c) {
                float4 v = reinterpret_cast<const float4*>(&Zs[t][cbase])[c];
                z16[c * 4 + 0] = v.x; z16[c * 4 + 1] = v.y;
                z16[c * 4 + 2] = v.z; z16[c * 4 + 3] = v.w;
            }
            float p = 0.f;
            #pragma unroll
            for (int c = 0; c < 16; ++c) p += wseg[c] * z16[c];
            p += __shfl_xor(p, 1, 4); p += __shfl_xor(p, 2, 4);
            wzr[g][t] = p + bgv[g];
        }
    }

    // ---- Phase C: 8 sequential GRU steps; U read from LDS (no global) ----
    #pragma unroll
    for (int t = 0; t < TSTEPS; ++t) {
        float q16[16];
        #pragma unroll
        for (int c = 0; c < 4; ++c) {
            float4 v = reinterpret_cast<const float4*>(&Qs[cbase])[c];
            q16[c * 4 + 0] = v.x; q16[c * 4 + 1] = v.y;
            q16[c * 4 + 2] = v.z; q16[c * 4 + 3] = v.w;
        }
        float u0v[16], u1v[16];
        #pragma unroll
        for (int cc = 0; cc < 4; ++cc) {
            float4 a = u4[0][cc][tid];
            u0v[cc * 4 + 0] = a.x; u0v[cc * 4 + 1] = a.y;
            u0v[cc * 4 + 2] = a.z; u0v[cc * 4 + 3] = a.w;
            float4 b = u4[1][cc][tid];
            u1v[cc * 4 + 0] = b.x; u1v[cc * 4 + 1] = b.y;
            u1v[cc * 4 + 2] = b.z; u1v[cc * 4 + 3] = b.w;
        }
        float p0 = 0.f, p1 = 0.f;
        #pragma unroll
        for (int c = 0; c < 16; ++c) { p0 += u0v[c] * q16[c]; p1 += u1v[c] * q16[c]; }
        p0 += __shfl_xor(p0, 1, 4); p0 += __shfl_xor(p0, 2, 4);
        p1 += __shfl_xor(p1, 1, 4); p1 += __shfl_xor(p1, 2, 4);
        const float qrow = Qs[row];
        const float zg = 1.f / (1.f + __expf(-(wzr[0][t] + p0)));
        const float rg = 1.f / (1.f + __expf(-(wzr[1][t] + p1)));
        if (quad == 0) rq[row] = rg * qrow;
        __syncthreads();
        float p2 = 0.f;
        {
            float r16[16], u2v[16];
            #pragma unroll
            for (int c = 0; c < 4; ++c) {
                float4 v = reinterpret_cast<const float4*>(&rq[cbase])[c];
                r16[c * 4 + 0] = v.x; r16[c * 4 + 1] = v.y;
                r16[c * 4 + 2] = v.z; r16[c * 4 + 3] = v.w;
                float4 u = u4[2][c][tid];
                u2v[c * 4 + 0] = u.x; u2v[c * 4 + 1] = u.y;
                u2v[c * 4 + 2] = u.z; u2v[c * 4 + 3] = u.w;
            }
            #pragma unroll
            for (int c = 0; c < 16; ++c) p2 += u2v[c] * r16[c];
        }
        p2 += __shfl_xor(p2, 1, 4); p2 += __shfl_xor(p2, 2, 4);
        const float hcap = tanhf(wzr[2][t] + p2);
        const float qn = (1.f - zg) * qrow + zg * hcap;
        if (quad == 0) {
            Qs[row] = qn;
            Qh[t][row] = qn;
        }
        __syncthreads();
    }

    // ---- restage W2 into the (now dead) U buffer, coalesced ----
    float* W2s = reinterpret_cast<float*>(&u4[0][0][0]);
    {
        const float4* W24 = reinterpret_cast<const float4*>(W2);
        float4* W2s4 = reinterpret_cast<float4*>(W2s);
        #pragma unroll
        for (int i = 0; i < 8; ++i) W2s4[i * TPB + tid] = W24[i * TPB + tid];
    }
    __syncthreads();

    // ---- Phase E: layer-2 GAT projection straight from Qh (as R15) ----
    const int lane = tid & 63;
    const int hh = tid >> 6;                 // head 0..3
    const int d2 = lane >> 1;                // 0..31
    const int fh = lane & 1;                 // f-half
    float w2seg[32];
    #pragma unroll
    for (int j = 0; j < 32; ++j)
        w2seg[j] = W2s[((size_t)(hh * 64 + fh * 32 + j)) * 32 + d2];
    const float a0 = a2[(hh * 2 + 0) * 32 + d2];
    const float a1 = a2[(hh * 2 + 1) * 32 + d2];
    #pragma unroll
    for (int t = 0; t < TSTEPS; ++t) {
        float q32[32];
        #pragma unroll
        for (int c = 0; c < 8; ++c) {
            float4 v = reinterpret_cast<const float4*>(&Qh[t][fh * 32])[c];
            q32[c * 4 + 0] = v.x; q32[c * 4 + 1] = v.y;
            q32[c * 4 + 2] = v.z; q32[c * 4 + 3] = v.w;
        }
        float p = 0.f;
        #pragma unroll
        for (int j = 0; j < 32; ++j) p += w2seg[j] * q32[j];
        p += __shfl_xor(p, 1, 64);           // combine both f-halves
        if (fh == 0) h2[(((size_t)t * NHEADS + hh) * NNODES + n) * 32 + d2] = p;
        float e0 = (fh == 0) ? p * a0 : 0.f;
        float e1 = (fh == 0) ? p * a1 : 0.f;
        #pragma unroll
        for (int s = 2; s <= 32; s <<= 1) {
            e0 += __shfl_xor(e0, s, 64);
            e1 += __shfl_xor(e1, s, 64);
        }
        if (lane == 0) {
            es2[((size_t)t * NHEADS + hh) * NNODES + n] = e0;
            ed2[((size_t)t * NHEADS + hh) * NNODES + n] = e1;
        }
    }
}

// ---------------------------------------------------------------------------
// K5: layer-2 fused wz+GRU (D=32), R7 version (best measured balance).
__global__ __launch_bounds__(64, 1)
void wzgru2_kernel(const float* __restrict__ Wg, const float* __restrict__ Ug,
                   const float* __restrict__ bg, const float* __restrict__ Z,
                   const float* __restrict__ q0, float* __restrict__ outp) {
    constexpr int D = 32;
    constexpr int TPB = 64;
    constexpr int F4R = D / 4;
    const int n = blockIdx.x, tid = threadIdx.x;
    const int quad = tid & 1;
    const int row  = tid >> 1;
    const int cbase = quad * 16;
    __shared__ float Zs[TSTEPS][D];
    __shared__ float Qs[D], rq[D];

    float wseg[3][16], useg[3][16];
    #pragma unroll
    for (int g = 0; g < 3; ++g) {
        const float4* W4 = reinterpret_cast<const float4*>(
            Wg + ((size_t)g * NNODES + n) * D * D + (size_t)row * D + cbase);
        #pragma unroll
        for (int c = 0; c < 4; ++c) {
            float4 v = W4[c];
            wseg[g][c * 4 + 0] = v.x; wseg[g][c * 4 + 1] = v.y;
            wseg[g][c * 4 + 2] = v.z; wseg[g][c * 4 + 3] = v.w;
        }
    }
    #pragma unroll
    for (int g = 0; g < 3; ++g) {
        const float4* U4 = reinterpret_cast<const float4*>(
            Ug + ((size_t)g * NNODES + n) * D * D + (size_t)row * D + cbase);
        #pragma unroll
        for (int c = 0; c < 4; ++c) {
            float4 v = U4[c];
            useg[g][c * 4 + 0] = v.x; useg[g][c * 4 + 1] = v.y;
            useg[g][c * 4 + 2] = v.z; useg[g][c * 4 + 3] = v.w;
        }
    }
    float bgv[3];
    #pragma unroll
    for (int g = 0; g < 3; ++g) bgv[g] = bg[((size_t)g * NNODES + n) * D + row];

    for (int idx = tid; idx < TSTEPS * F4R; idx += TPB) {
        int t = idx / F4R, i4 = idx % F4R;
        reinterpret_cast<float4*>(&Zs[t][0])[i4] =
            reinterpret_cast<const float4*>(Z + ((size_t)t * NNODES + n) * D)[i4];
    }
    if (tid < D) Qs[tid] = q0[(size_t)n * D + tid];
    __syncthreads();

    float wzr[3][TSTEPS];
    #pragma unroll
    for (int t = 0; t < TSTEPS; ++t) {
        float z16[16];
        #pragma unroll
        for (int c = 0; c < 4; ++c) {
            float4 v = reinterpret_cast<const float4*>(&Zs[t][cbase])[c];
            z16[c * 4 + 0] = v.x; z16[c * 4 + 1] = v.y;
            z16[c * 4 + 2] = v.z; z16[c * 4 + 3] = v.w;
        }
        #pragma unroll
        for (int g = 0; g < 3; ++g) {
            float p = 0.f;
            #pragma unroll
            for (int c = 0; c < 16; ++c) p += wseg[g][c] * z16[c];
            p += __shfl_xor(p, 1, 2);
            wzr[g][t] = p + bgv[g];
        }
    }

    #pragma unroll
    for (int t = 0; t < TSTEPS; ++t) {
        float q16[16];
        #pragma unroll
        for (int c = 0; c < 4; ++c) {
            float4 v = reinterpret_cast<const float4*>(&Qs[cbase])[c];
            q16[c * 4 + 0] = v.x; q16[c * 4 + 1] = v.y;
            q16[c * 4 + 2] = v.z; q16[c * 4 + 3] = v.w;
        }
        float p0 = 0.f, p1 = 0.f;
        #pragma unroll
        for (int c = 0; c < 16; ++c) { p0 += useg[0][c] * q16[c]; p1 += useg[1][c] * q16[c]; }
        p0 += __shfl_xor(p0, 1, 2);
        p1 += __shfl_xor(p1, 1, 2);
        const float qrow = Qs[row];
        const float zg = 1.f / (1.f + __expf(-(wzr[0][t] + p0)));
        const float rg = 1.f / (1.f + __expf(-(wzr[1][t] + p1)));
        if (quad == 0) rq[row] = rg * qrow;
        __syncthreads();
        float p2 = 0.f;
        {
            float r16[16];
            #pragma unroll
            for (int c = 0; c < 4; ++c) {
                float4 v = reinterpret_cast<const float4*>(&rq[cbase])[c];
                r16[c * 4 + 0] = v.x; r16[c * 4 + 1] = v.y;
                r16[c * 4 + 2] = v.z; r16[c * 4 + 3] = v.w;
            }
            #pragma unroll
            for (int c = 0; c < 16; ++c) p2 += useg[2][c] * r16[c];
        }
        p2 += __shfl_xor(p2, 1, 2);
        const float hcap = tanhf(wzr[2][t] + p2);
        const float qn = (1.f - zg) * qrow + zg * hcap;
        if (quad == 0) {
            Qs[row] = qn;
            outp[((size_t)t * NNODES + n) * D + row] = qn;
        }
        __syncthreads();
    }
}

// ---------------------------------------------------------------------------
extern "C" void kernel_launch(void* const* d_in, const int* in_sizes, int n_in,
                              void* d_out, int out_size, void* d_ws, size_t ws_size,
                              hipStream_t stream) {
    const float* A      = (const float*)d_in[0];
    const float* feats  = (const float*)d_in[1];
    const float* gat1_W = (const float*)d_in[2];
    const float* gat1_a = (const float*)d_in[3];
    const float* gru1_W = (const float*)d_in[4];
    const float* gru1_U = (const float*)d_in[5];
    const float* gru1_b = (const float*)d_in[6];
    const float* q1     = (const float*)d_in[7];
    const float* gat2_W = (const float*)d_in[8];
    const float* gat2_a = (const float*)d_in[9];
    const float* gru2_W = (const float*)d_in[10];
    const float* gru2_U = (const float*)d_in[11];
    const float* gru2_b = (const float*)d_in[12];
    const float* q2     = (const float*)d_in[13];
    float* out = (float*)d_out;

    // Workspace layout (~22 MB)
    char* ws = (char*)d_ws;
    int*   nbr  = (int*)ws;    ws += (size_t)NROWS * CAP * 4;
    int*   cnt  = (int*)ws;    ws += (size_t)NROWS * 4;
    float* h1   = (float*)ws;  ws += (size_t)TSTEPS * NHEADS * NNODES * 16 * 4;
    float* es1  = (float*)ws;  ws += (size_t)TSTEPS * NHEADS * NNODES * 4;
    float* ed1  = (float*)ws;  ws += (size_t)TSTEPS * NHEADS * NNODES * 4;
    float* Z1   = (float*)ws;  ws += (size_t)TSTEPS * NNODES * 64 * 4;
    float* h2   = (float*)ws;  ws += (size_t)TSTEPS * NHEADS * NNODES * 32 * 4;
    float* es2  = (float*)ws;  ws += (size_t)TSTEPS * NHEADS * NNODES * 4;
    float* ed2  = (float*)ws;  ws += (size_t)TSTEPS * NHEADS * NNODES * 4;
    float* Z2   = (float*)ws;  ws += (size_t)TSTEPS * NNODES * 32 * 4;

    // K1: CSR build (HBM-bound A-scan) overlapped with layer-1 GAT projection
    k1_csr_gath1<<<2 * NROWS, 64, 0, stream>>>(A, nbr, cnt, feats, gat1_W, gat1_a,
                                               h1, es1, ed1);
    // K2: layer-1 sparse attention -> Z1 (no-max softmax, exp-folded staging)
    gat_attn_all_kernel<16, true><<<NROWS, 64, 0, stream>>>(nbr, cnt, h1, es1, ed1, Z1);
    // K3: layer-1 fused wz+GRU + layer-2 projection (U in LDS, zero global
    //     loads in the serial phases)
    wzgru1_gath2_kernel<<<NNODES, 256, 0, stream>>>(gru1_W, gru1_U, gru1_b, Z1, q1,
                                                    gat2_W, gat2_a, h2, es2, ed2);
    // K4: layer-2 sparse attention -> Z2 (no-max softmax, exp-folded staging)
    gat_attn_all_kernel<32, false><<<NROWS, 128, 0, stream>>>(nbr, cnt, h2, es2, ed2, Z2);
    // K5: layer-2 fused wz+GRU -> out
    wzgru2_kernel<<<NNODES, 64, 0, stream>>>(gru2_W, gru2_U, gru2_b, Z2, q2, out);
}

// Round 17
// 150.267 us; speedup vs baseline: 1.0991x; 1.0991x over previous
//
#include <hip/hip_runtime.h>
#include <cstdint>
#include <cstddef>

// Problem constants (fixed by the reference setup)
#define NNODES 2000
#define TSTEPS 8
#define NHEADS 4
#define CAP    96      // max neighbors; degree ~ Binom(2000,0.01)+self ≈ 21±4.5, 96 is >16σ
#define NROWS  (TSTEPS * NNODES)   // 16000

// ---------------------------------------------------------------------------
// K1: blocks [0,NROWS) build CSR rows (float4 scan + 4 ordered ballots);
//     blocks [NROWS,2*NROWS) compute layer-1 GAT projection h1/es1/ed1.
__global__ void k1_csr_gath1(const float* __restrict__ A,
                             int* __restrict__ nbr, int* __restrict__ cnt,
                             const float* __restrict__ feats,
                             const float* __restrict__ W, const float* __restrict__ a,
                             float* __restrict__ hbuf, float* __restrict__ es,
                             float* __restrict__ ed) {
    const int lane = threadIdx.x;            // 64
    if (blockIdx.x < NROWS) {
        const int row = blockIdx.x;          // t*N + n
        const float4* Ar4 = reinterpret_cast<const float4*>(A + (size_t)row * NNODES);
        int* outp = nbr + (size_t)row * CAP;
        const unsigned long long lmask = (1ull << lane) - 1ull;
        int c = 0;
        for (int j4 = lane; j4 < NNODES / 4; j4 += 64) {   // 500 float4 per row
            float4 v = Ar4[j4];
            #pragma unroll
            for (int cc = 0; cc < 4; ++cc) {
                float x = (cc == 0) ? v.x : (cc == 1) ? v.y : (cc == 2) ? v.z : v.w;
                bool p = x > 0.0f;
                unsigned long long m = __ballot(p);
                int off = __popcll(m & lmask);
                if (p && c + off < CAP) outp[c + off] = j4 * 4 + cc;
                c += (int)__popcll(m);
            }
        }
        if (lane == 0) cnt[row] = (c > CAP ? CAP : c);
    } else {
        const int b = blockIdx.x - NROWS;    // t*N + n
        const int t = b / NNODES, n = b % NNODES;
        constexpr int F = 32, D = 16;
        const int h = lane / D, d = lane % D;
        const float* xr = feats + (size_t)b * F;
        const float* Wp = W + (size_t)h * F * D + d;
        float acc = 0.f;
        #pragma unroll
        for (int f = 0; f < F; ++f) acc += xr[f] * Wp[f * D];
        hbuf[(((size_t)t * NHEADS + h) * NNODES + n) * D + d] = acc;
        float s0 = acc * a[(h * 2 + 0) * D + d];
        float s1 = acc * a[(h * 2 + 1) * D + d];
        #pragma unroll
        for (int s = D / 2; s > 0; s >>= 1) {
            s0 += __shfl_down(s0, s, D);
            s1 += __shfl_down(s1, s, D);
        }
        if (d == 0) {
            es[((size_t)t * NHEADS + h) * NNODES + n] = s0;
            ed[((size_t)t * NHEADS + h) * NNODES + n] = s1;
        }
    }
}

// ---------------------------------------------------------------------------
// K2/K4: sparse masked softmax + aggregate, all t. NO max-subtraction pass:
// the reference's row-max shift exists only to neutralize the -1e9 masked
// logits, which our sparse iteration never touches. Real logits are
// leaky_relu(es+ed) = O(1), far below exp-overflow. Softmax is
// shift-invariant, so exp(v)/sum is mathematically identical.
template<int D, bool CONCAT>
__global__ void gat_attn_all_kernel(const int* __restrict__ nbr, const int* __restrict__ cnt_arr,
                                    const float* __restrict__ hbuf, const float* __restrict__ es,
                                    const float* __restrict__ ed, float* __restrict__ Z) {
    const int b = blockIdx.x;
    const int t = b / NNODES, n = b % NNODES;
    const int tid = threadIdx.x;
    const int h = tid / D, d = tid % D;
    const int cnt = cnt_arr[b];
    const int* idx = nbr + (size_t)b * CAP;
    const float* esb = es + (size_t)t * NHEADS * NNODES;
    const float* edb = ed + (size_t)t * NHEADS * NNODES;
    const float* hb  = hbuf + (size_t)t * NHEADS * NNODES * D;
    __shared__ int mlist[CAP];
    __shared__ float eds[NHEADS][CAP];
    for (int k = tid; k < cnt; k += NHEADS * D) mlist[k] = idx[k];
    __syncthreads();
    for (int k = d; k < cnt; k += D) eds[h][k] = edb[(size_t)h * NNODES + mlist[k]];
    __syncthreads();
    const float esv = esb[(size_t)h * NNODES + n];
    float wsum = 0.f, acc = 0.f;
    for (int k = 0; k < cnt; ++k) {
        float v = esv + eds[h][k];
        v = v > 0.f ? v : 0.2f * v;          // leaky_relu(0.2)
        float w = __expf(v);                 // shift-invariant: no max needed
        wsum += w;
        acc += w * hb[((size_t)h * NNODES + mlist[k]) * D + d];
    }
    float o = acc / wsum;
    if constexpr (CONCAT) {
        float e = o > 0.f ? o : (__expf(o) - 1.0f);       // elu
        Z[(size_t)b * (NHEADS * D) + h * D + d] = e;      // [T][N][H*D]
    } else {
        __shared__ float red[NHEADS][D];
        red[h][d] = o;
        __syncthreads();
        if (h == 0) Z[(size_t)b * D + d] =
            (red[0][d] + red[1][d] + red[2][d] + red[3][d]) * 0.25f;  // mean heads, no elu
    }
}

// ---------------------------------------------------------------------------
// K3: layer-1 fused wz+GRU (D=64) + layer-2 GAT projection epilogue.
// R7 register/occupancy balance (VGPR 72, occ ~28% — measured optimum of the
// R4..R16 VGPR/LDS/occupancy ladder); W2 staged once into LDS (coalesced).
__global__ __launch_bounds__(256, 1)
void wzgru1_gath2_kernel(const float* __restrict__ Wg, const float* __restrict__ Ug,
                         const float* __restrict__ bg, const float* __restrict__ Z,
                         const float* __restrict__ q0,
                         const float* __restrict__ W2, const float* __restrict__ a2,
                         float* __restrict__ h2, float* __restrict__ es2,
                         float* __restrict__ ed2) {
    constexpr int D = 64;
    constexpr int TPB = 256;
    constexpr int F4R = D / 4;               // float4 per matrix row
    const int n = blockIdx.x, tid = threadIdx.x;
    const int quad = tid & 3;
    const int row  = tid >> 2;
    const int cbase = quad * 16;
    __shared__ float Zs[TSTEPS][D];
    __shared__ float Qh[TSTEPS][D];          // s1 rows for this node, all t
    __shared__ float Qs[D], rq[D];
    __shared__ float W2s[NHEADS * 64 * 32];  // 32KB: staged coalesced once

    // stage W2 coalesced (8 float4/thread); consumed in phase E
    {
        const float4* W24 = reinterpret_cast<const float4*>(W2);
        float4* W2s4 = reinterpret_cast<float4*>(W2s);
        #pragma unroll
        for (int i = 0; i < 8; ++i) W2s4[i * TPB + tid] = W24[i * TPB + tid];
    }

    // W gate row segments -> registers
    float wseg[3][16], useg[3][16];
    #pragma unroll
    for (int g = 0; g < 3; ++g) {
        const float4* W4 = reinterpret_cast<const float4*>(
            Wg + ((size_t)g * NNODES + n) * D * D + (size_t)row * D + cbase);
        #pragma unroll
        for (int c = 0; c < 4; ++c) {
            float4 v = W4[c];
            wseg[g][c * 4 + 0] = v.x; wseg[g][c * 4 + 1] = v.y;
            wseg[g][c * 4 + 2] = v.z; wseg[g][c * 4 + 3] = v.w;
        }
    }
    float bgv[3];
    #pragma unroll
    for (int g = 0; g < 3; ++g) bgv[g] = bg[((size_t)g * NNODES + n) * D + row];

    // Z (all t) + Q0 into LDS
    for (int idx = tid; idx < TSTEPS * F4R; idx += TPB) {
        int t = idx / F4R, i4 = idx % F4R;
        reinterpret_cast<float4*>(&Zs[t][0])[i4] =
            reinterpret_cast<const float4*>(Z + ((size_t)t * NNODES + n) * D)[i4];
    }
    if (tid < D) Qs[tid] = q0[(size_t)n * D + tid];
    __syncthreads();   // Zs, Qs (and W2s) ready

    // ---- Phase B: wz[g][t] -> registers (butterfly broadcasts to all quads) ----
    float wzr[3][TSTEPS];
    #pragma unroll
    for (int t = 0; t < TSTEPS; ++t) {
        float z16[16];
        #pragma unroll
        for (int c = 0; c < 4; ++c) {
            float4 v = reinterpret_cast<const float4*>(&Zs[t][cbase])[c];
            z16[c * 4 + 0] = v.x; z16[c * 4 + 1] = v.y;
            z16[c * 4 + 2] = v.z; z16[c * 4 + 3] = v.w;
        }
        #pragma unroll
        for (int g = 0; g < 3; ++g) {
            float p = 0.f;
            #pragma unroll
            for (int c = 0; c < 16; ++c) p += wseg[g][c] * z16[c];
            p += __shfl_xor(p, 1, 4); p += __shfl_xor(p, 2, 4);
            wzr[g][t] = p + bgv[g];
        }
    }

    // U row segments -> registers (issued here, consumed in phase C)
    #pragma unroll
    for (int g = 0; g < 3; ++g) {
        const float4* U4 = reinterpret_cast<const float4*>(
            Ug + ((size_t)g * NNODES + n) * D * D + (size_t)row * D + cbase);
        #pragma unroll
        for (int c = 0; c < 4; ++c) {
            float4 v = U4[c];
            useg[g][c * 4 + 0] = v.x; useg[g][c * 4 + 1] = v.y;
            useg[g][c * 4 + 2] = v.z; useg[g][c * 4 + 3] = v.w;
        }
    }

    // ---- Phase C: 8 sequential GRU steps; Q history recorded in LDS ----
    #pragma unroll
    for (int t = 0; t < TSTEPS; ++t) {
        float q16[16];
        #pragma unroll
        for (int c = 0; c < 4; ++c) {
            float4 v = reinterpret_cast<const float4*>(&Qs[cbase])[c];
            q16[c * 4 + 0] = v.x; q16[c * 4 + 1] = v.y;
            q16[c * 4 + 2] = v.z; q16[c * 4 + 3] = v.w;
        }
        float p0 = 0.f, p1 = 0.f;
        #pragma unroll
        for (int c = 0; c < 16; ++c) { p0 += useg[0][c] * q16[c]; p1 += useg[1][c] * q16[c]; }
        p0 += __shfl_xor(p0, 1, 4); p0 += __shfl_xor(p0, 2, 4);
        p1 += __shfl_xor(p1, 1, 4); p1 += __shfl_xor(p1, 2, 4);
        const float qrow = Qs[row];
        const float zg = 1.f / (1.f + __expf(-(wzr[0][t] + p0)));
        const float rg = 1.f / (1.f + __expf(-(wzr[1][t] + p1)));
        if (quad == 0) rq[row] = rg * qrow;
        __syncthreads();
        float p2 = 0.f;
        {
            float r16[16];
            #pragma unroll
            for (int c = 0; c < 4; ++c) {
                float4 v = reinterpret_cast<const float4*>(&rq[cbase])[c];
                r16[c * 4 + 0] = v.x; r16[c * 4 + 1] = v.y;
                r16[c * 4 + 2] = v.z; r16[c * 4 + 3] = v.w;
            }
            #pragma unroll
            for (int c = 0; c < 16; ++c) p2 += useg[2][c] * r16[c];
        }
        p2 += __shfl_xor(p2, 1, 4); p2 += __shfl_xor(p2, 2, 4);
        const float hcap = tanhf(wzr[2][t] + p2);
        const float qn = (1.f - zg) * qrow + zg * hcap;
        if (quad == 0) {
            Qs[row] = qn;
            Qh[t][row] = qn;
        }
        __syncthreads();
    }

    // ---- Phase E: layer-2 GAT projection straight from Qh ----
    const int lane = tid & 63;
    const int hh = tid >> 6;                 // head 0..3
    const int d2 = lane >> 1;                // 0..31
    const int fh = lane & 1;                 // f-half
    float w2seg[32];
    #pragma unroll
    for (int j = 0; j < 32; ++j)
        w2seg[j] = W2s[((size_t)(hh * 64 + fh * 32 + j)) * 32 + d2];
    const float a0 = a2[(hh * 2 + 0) * 32 + d2];
    const float a1 = a2[(hh * 2 + 1) * 32 + d2];
    #pragma unroll
    for (int t = 0; t < TSTEPS; ++t) {
        float q32[32];
        #pragma unroll
        for (int c = 0; c < 8; ++c) {
            float4 v = reinterpret_cast<const float4*>(&Qh[t][fh * 32])[c];
            q32[c * 4 + 0] = v.x; q32[c * 4 + 1] = v.y;
            q32[c * 4 + 2] = v.z; q32[c * 4 + 3] = v.w;
        }
        float p = 0.f;
        #pragma unroll
        for (int j = 0; j < 32; ++j) p += w2seg[j] * q32[j];
        p += __shfl_xor(p, 1, 64);           // combine both f-halves
        if (fh == 0) h2[(((size_t)t * NHEADS + hh) * NNODES + n) * 32 + d2] = p;
        float e0 = (fh == 0) ? p * a0 : 0.f;
        float e1 = (fh == 0) ? p * a1 : 0.f;
        #pragma unroll
        for (int s = 2; s <= 32; s <<= 1) {
            e0 += __shfl_xor(e0, s, 64);
            e1 += __shfl_xor(e1, s, 64);
        }
        if (lane == 0) {
            es2[((size_t)t * NHEADS + hh) * NNODES + n] = e0;
            ed2[((size_t)t * NHEADS + hh) * NNODES + n] = e1;
        }
    }
}

// ---------------------------------------------------------------------------
// K5: layer-2 fused wz+GRU (D=32), R7 version (best measured balance).
__global__ __launch_bounds__(64, 1)
void wzgru2_kernel(const float* __restrict__ Wg, const float* __restrict__ Ug,
                   const float* __restrict__ bg, const float* __restrict__ Z,
                   const float* __restrict__ q0, float* __restrict__ outp) {
    constexpr int D = 32;
    constexpr int TPB = 64;
    constexpr int F4R = D / 4;
    const int n = blockIdx.x, tid = threadIdx.x;
    const int quad = tid & 1;
    const int row  = tid >> 1;
    const int cbase = quad * 16;
    __shared__ float Zs[TSTEPS][D];
    __shared__ float Qs[D], rq[D];

    float wseg[3][16], useg[3][16];
    #pragma unroll
    for (int g = 0; g < 3; ++g) {
        const float4* W4 = reinterpret_cast<const float4*>(
            Wg + ((size_t)g * NNODES + n) * D * D + (size_t)row * D + cbase);
        #pragma unroll
        for (int c = 0; c < 4; ++c) {
            float4 v = W4[c];
            wseg[g][c * 4 + 0] = v.x; wseg[g][c * 4 + 1] = v.y;
            wseg[g][c * 4 + 2] = v.z; wseg[g][c * 4 + 3] = v.w;
        }
    }
    #pragma unroll
    for (int g = 0; g < 3; ++g) {
        const float4* U4 = reinterpret_cast<const float4*>(
            Ug + ((size_t)g * NNODES + n) * D * D + (size_t)row * D + cbase);
        #pragma unroll
        for (int c = 0; c < 4; ++c) {
            float4 v = U4[c];
            useg[g][c * 4 + 0] = v.x; useg[g][c * 4 + 1] = v.y;
            useg[g][c * 4 + 2] = v.z; useg[g][c * 4 + 3] = v.w;
        }
    }
    float bgv[3];
    #pragma unroll
    for (int g = 0; g < 3; ++g) bgv[g] = bg[((size_t)g * NNODES + n) * D + row];

    for (int idx = tid; idx < TSTEPS * F4R; idx += TPB) {
        int t = idx / F4R, i4 = idx % F4R;
        reinterpret_cast<float4*>(&Zs[t][0])[i4] =
            reinterpret_cast<const float4*>(Z + ((size_t)t * NNODES + n) * D)[i4];
    }
    if (tid < D) Qs[tid] = q0[(size_t)n * D + tid];
    __syncthreads();

    float wzr[3][TSTEPS];
    #pragma unroll
    for (int t = 0; t < TSTEPS; ++t) {
        float z16[16];
        #pragma unroll
        for (int c = 0; c < 4; ++c) {
            float4 v = reinterpret_cast<const float4*>(&Zs[t][cbase])[c];
            z16[c * 4 + 0] = v.x; z16[c * 4 + 1] = v.y;
            z16[c * 4 + 2] = v.z; z16[c * 4 + 3] = v.w;
        }
        #pragma unroll
        for (int g = 0; g < 3; ++g) {
            float p = 0.f;
            #pragma unroll
            for (int c = 0; c < 16; ++c) p += wseg[g][c] * z16[c];
            p += __shfl_xor(p, 1, 2);
            wzr[g][t] = p + bgv[g];
        }
    }

    #pragma unroll
    for (int t = 0; t < TSTEPS; ++t) {
        float q16[16];
        #pragma unroll
        for (int c = 0; c < 4; ++c) {
            float4 v = reinterpret_cast<const float4*>(&Qs[cbase])[c];
            q16[c * 4 + 0] = v.x; q16[c * 4 + 1] = v.y;
            q16[c * 4 + 2] = v.z; q16[c * 4 + 3] = v.w;
        }
        float p0 = 0.f, p1 = 0.f;
        #pragma unroll
        for (int c = 0; c < 16; ++c) { p0 += useg[0][c] * q16[c]; p1 += useg[1][c] * q16[c]; }
        p0 += __shfl_xor(p0, 1, 2);
        p1 += __shfl_xor(p1, 1, 2);
        const float qrow = Qs[row];
        const float zg = 1.f / (1.f + __expf(-(wzr[0][t] + p0)));
        const float rg = 1.f / (1.f + __expf(-(wzr[1][t] + p1)));
        if (quad == 0) rq[row] = rg * qrow;
        __syncthreads();
        float p2 = 0.f;
        {
            float r16[16];
            #pragma unroll
            for (int c = 0; c < 4; ++c) {
                float4 v = reinterpret_cast<const float4*>(&rq[cbase])[c];
                r16[c * 4 + 0] = v.x; r16[c * 4 + 1] = v.y;
                r16[c * 4 + 2] = v.z; r16[c * 4 + 3] = v.w;
            }
            #pragma unroll
            for (int c = 0; c < 16; ++c) p2 += useg[2][c] * r16[c];
        }
        p2 += __shfl_xor(p2, 1, 2);
        const float hcap = tanhf(wzr[2][t] + p2);
        const float qn = (1.f - zg) * qrow + zg * hcap;
        if (quad == 0) {
            Qs[row] = qn;
            outp[((size_t)t * NNODES + n) * D + row] = qn;
        }
        __syncthreads();
    }
}

// ---------------------------------------------------------------------------
extern "C" void kernel_launch(void* const* d_in, const int* in_sizes, int n_in,
                              void* d_out, int out_size, void* d_ws, size_t ws_size,
                              hipStream_t stream) {
    const float* A      = (const float*)d_in[0];
    const float* feats  = (const float*)d_in[1];
    const float* gat1_W = (const float*)d_in[2];
    const float* gat1_a = (const float*)d_in[3];
    const float* gru1_W = (const float*)d_in[4];
    const float* gru1_U = (const float*)d_in[5];
    const float* gru1_b = (const float*)d_in[6];
    const float* q1     = (const float*)d_in[7];
    const float* gat2_W = (const float*)d_in[8];
    const float* gat2_a = (const float*)d_in[9];
    const float* gru2_W = (const float*)d_in[10];
    const float* gru2_U = (const float*)d_in[11];
    const float* gru2_b = (const float*)d_in[12];
    const float* q2     = (const float*)d_in[13];
    float* out = (float*)d_out;

    // Workspace layout (~22 MB)
    char* ws = (char*)d_ws;
    int*   nbr  = (int*)ws;    ws += (size_t)NROWS * CAP * 4;
    int*   cnt  = (int*)ws;    ws += (size_t)NROWS * 4;
    float* h1   = (float*)ws;  ws += (size_t)TSTEPS * NHEADS * NNODES * 16 * 4;
    float* es1  = (float*)ws;  ws += (size_t)TSTEPS * NHEADS * NNODES * 4;
    float* ed1  = (float*)ws;  ws += (size_t)TSTEPS * NHEADS * NNODES * 4;
    float* Z1   = (float*)ws;  ws += (size_t)TSTEPS * NNODES * 64 * 4;
    float* h2   = (float*)ws;  ws += (size_t)TSTEPS * NHEADS * NNODES * 32 * 4;
    float* es2  = (float*)ws;  ws += (size_t)TSTEPS * NHEADS * NNODES * 4;
    float* ed2  = (float*)ws;  ws += (size_t)TSTEPS * NHEADS * NNODES * 4;
    float* Z2   = (float*)ws;  ws += (size_t)TSTEPS * NNODES * 32 * 4;

    // K1: CSR build (HBM-bound A-scan) overlapped with layer-1 GAT projection
    k1_csr_gath1<<<2 * NROWS, 64, 0, stream>>>(A, nbr, cnt, feats, gat1_W, gat1_a,
                                               h1, es1, ed1);
    // K2: layer-1 sparse attention -> Z1 (no-max softmax)
    gat_attn_all_kernel<16, true><<<NROWS, 64, 0, stream>>>(nbr, cnt, h1, es1, ed1, Z1);
    // K3: layer-1 fused wz+GRU + layer-2 projection (s1 stays on-chip)
    wzgru1_gath2_kernel<<<NNODES, 256, 0, stream>>>(gru1_W, gru1_U, gru1_b, Z1, q1,
                                                    gat2_W, gat2_a, h2, es2, ed2);
    // K4: layer-2 sparse attention -> Z2 (no-max softmax)
    gat_attn_all_kernel<32, false><<<NROWS, 128, 0, stream>>>(nbr, cnt, h2, es2, ed2, Z2);
    // K5: layer-2 fused wz+GRU -> out
    wzgru2_kernel<<<NNODES, 64, 0, stream>>>(gru2_W, gru2_U, gru2_b, Z2, q2, out);
}